// Round 15
// baseline (227.437 us; speedup 1.0000x reference)
//
#include <hip/hip_runtime.h>
#include <hip/hip_bf16.h>

#define NL 2
#define NH 8
#define DKk 32
#define DVv 32
#define DFF 512
#define DD 256
#define BB 2
#define SS 2048
#define MROWS (BB*SS)            // 4096
#define LN_EPS 1e-14f
#define L2E 1.4426950408889634f
#define SOFT_SHIFT_L2E (50.0f*L2E)   // fixed softmax shift, in log2 units

typedef __hip_bfloat16 bf16;
typedef unsigned short us;
typedef short bf16x8 __attribute__((ext_vector_type(8)));   // 8 bf16 = 4 VGPRs
typedef float f32x4  __attribute__((ext_vector_type(4)));
typedef unsigned short us4 __attribute__((ext_vector_type(4)));

// ---- workspace layout (floats) ----
#define O_XF   256
#define O_QB   (O_XF+1048576)      // QH (1048576 us) + QL (1048576 us) frag-major
#define O_KH   (O_QB+1048576)
#define O_KL   (O_KH+524288)
#define O_VT   (O_KL+524288)
#define O_XH   (O_VT+524288)       // x pre-split hi (1048576 us)
#define O_XL   (O_XH+524288)       // x pre-split lo
#define O_OP   (O_XL+524288)       // 2097152: key-split x2 partial O
#define O_ML   (O_OP+2097152)      // 65536: key-split l (m is constant)
#define O_MASK (O_ML+65536)
#define O_B1   (O_MASK+4096)
#define O_B2   (O_B1+1024)
#define O_GM   (O_B2+512)
#define O_BT   (O_GM+4)
#define O_PREP (O_BT+4)
// conv: x handled 8-wide by 512 blocks; tail segments (mask|b1|b2|gamma|beta)
#define TAIL_TOTAL (4096+1024+512+4+4)
#define CONV_BLOCKS (512 + (TAIL_TOTAL+255)/256)
#define PREP_BLOCKS 512
// prep region offsets in ushorts (relative to (us*)(ws+O_PREP))
#define PQH 0u
#define PQL 393216u
#define POH 786432u
#define POL 917504u
#define P1H 1048576u
#define P1L 1310720u
#define P2H 1572864u
#define P2L 1835008u

__device__ __forceinline__ float us2f(us u){
  unsigned int v = ((unsigned int)u) << 16; float f;
  __builtin_memcpy(&f, &v, 4); return f;
}
__device__ __forceinline__ us f2bf_rne(float f){
  unsigned int b = __float_as_uint(f);
  b += 0x7FFFu + ((b>>16)&1u);
  return (us)(b>>16);
}

#if __has_builtin(__builtin_amdgcn_exp2f)
#define EXP2F(x) __builtin_amdgcn_exp2f(x)
#else
#define EXP2F(x) exp2f(x)
#endif

#if __has_builtin(__builtin_amdgcn_cvt_pk_bf16_f32)
typedef __bf16 bf16x2_t __attribute__((ext_vector_type(2)));
__device__ __forceinline__ int pack_bf16(float a, float b){
  bf16x2_t r = __builtin_amdgcn_cvt_pk_bf16_f32(a, b);
  int i; __builtin_memcpy(&i, &r, 4); return i;
}
#else
__device__ __forceinline__ int pack_bf16(float a, float b){
  int b0 = __float_as_int(a) + 0x8000;
  int b1 = __float_as_int(b) + 0x8000;
  return (b1 & 0xFFFF0000) | ((int)((unsigned)b0 >> 16));
}
#endif

__device__ __forceinline__ f32x4 MF(bf16x8 a, bf16x8 b, f32x4 c){
  return __builtin_amdgcn_mfma_f32_16x16x32_bf16(a,b,c,0,0,0);
}

// Async global->LDS 16B copy (lane-linear layouts only).
__device__ __forceinline__ void gl_lds16(const us* g, us* l){
  __builtin_amdgcn_global_load_lds(
    (const __attribute__((address_space(1))) unsigned int*)g,
    (__attribute__((address_space(3))) unsigned int*)l, 16, 0, 0);
}

// x pre-split frag-major index for element (row, col), K=256 tiling.
__device__ __forceinline__ size_t xhl_idx(int row, int col){
  int rt = row>>6, rg = (row>>4)&3, L15 = row&15;
  int kc = col>>5, Q = (col>>3)&3, j = col&7;
  return ((size_t)(rt*8+kc))*2048 + rg*512 + Q*128 + L15*8 + j;
}

__device__ __forceinline__ float conv1(const void* src, size_t i, int flag){
  if(flag) return ((const float*)src)[i];
  return us2f(((const us*)src)[i]);
}

// Build fragment-major hi/lo bf16 B-operands reading RAW (flag-dtype) weights.
__device__ __forceinline__ void prep_b_raw(const void* W0, const void* W1v, const void* W2v,
                                           int baseoff, us* __restrict__ Bh, us* __restrict__ Bl,
                                           int Kd, int Nd, int qkv, int g, int flag)
{
  int total = (Kd/32)*(Nd/16)*64;
  if(g >= total) return;
  int lane = g & 63, fi = g >> 6;
  int ncN = Nd/16;
  int nc = fi % ncN, kc = fi / ncN;
  int Q = lane>>4, L15 = lane&15;
  int n = nc*16 + L15;
  const void* src;
  int off0, stride;
  if(qkv){
    int sec = n>>8, h = (n>>5)&7, kq = n&31;
    src = (sec==0)?W0:((sec==1)?W1v:W2v);
    off0 = baseoff + h*8192 + kq;
    stride = 32;
  } else {
    src = W0;
    off0 = baseoff + n;
    stride = Nd;
  }
  #pragma unroll
  for(int j=0;j<8;j++){
    int k = kc*32 + Q*8 + j;
    float v = conv1(src, (size_t)off0 + (size_t)k*stride, flag);
    us hb = f2bf_rne(v);
    Bh[(size_t)g*8 + j] = hb;
    Bl[(size_t)g*8 + j] = f2bf_rne(v - us2f(hb));
  }
}

// Fused: dtype-detect (per-block) + weight prep (blocks 0..511) + input conversion.
// x conversion is 8-wide per thread (16B loads, 16B frag-major stores).
__global__ void conv_prep(const void* s0, const void* s1, const void* sWq, const void* sWk,
                          const void* sWv, const void* sWo, const void* sW1, const void* sb1,
                          const void* sW2, const void* sb2, const void* sgm, const void* sbt,
                          float* __restrict__ ws, int* __restrict__ flagp)
{
  __shared__ int fsh[4];
  int bad = 0;
  const us* xr = (const us*)s0;
  for(int i=threadIdx.x; i<4096; i+=256){
    float f = us2f(xr[i]);
    if(!(fabsf(f) < 1e3f)) bad = 1;
  }
  unsigned long long m = __ballot(bad);
  if((threadIdx.x&63)==0) fsh[threadIdx.x>>6] = (m!=0ull);
  __syncthreads();
  int flag = (fsh[0]|fsh[1]|fsh[2]|fsh[3]);
  if(blockIdx.x==0 && threadIdx.x==0) *flagp = flag;

  int b = blockIdx.x;
  if(b < PREP_BLOCKS){
    int layer = b >> 8, lb = b & 255;
    us* prep = (us*)(ws + O_PREP);
    if(lb < 96){
      int g = lb*256 + threadIdx.x;
      prep_b_raw(sWq, sWk, sWv, layer*65536, prep+PQH+(size_t)layer*196608,
                 prep+PQL+(size_t)layer*196608, 256, 768, 1, g, flag);
    } else if(lb < 128){
      int g = (lb-96)*256 + threadIdx.x;
      prep_b_raw(sWo, nullptr, nullptr, layer*65536, prep+POH+(size_t)layer*65536,
                 prep+POL+(size_t)layer*65536, 256, 256, 0, g, flag);
    } else if(lb < 192){
      int g = (lb-128)*256 + threadIdx.x;
      prep_b_raw(sW1, nullptr, nullptr, layer*131072, prep+P1H+(size_t)layer*131072,
                 prep+P1L+(size_t)layer*131072, 256, 512, 0, g, flag);
    } else {
      int g = (lb-192)*256 + threadIdx.x;
      prep_b_raw(sW2, nullptr, nullptr, layer*131072, prep+P2H+(size_t)layer*131072,
                 prep+P2L+(size_t)layer*131072, 512, 256, 0, g, flag);
    }
    return;
  }
  int b2 = b - PREP_BLOCKS;
  if(b2 < 512){
    // x: 8 consecutive elements per thread (one row, 8-aligned col block).
    int g8 = b2*256 + threadIdx.x;       // 0..131071
    int e0 = g8*8;
    float v[8];
    if(flag){
      float4 a0 = *((const float4*)s0 + (e0>>2));
      float4 a1 = *((const float4*)s0 + (e0>>2) + 1);
      v[0]=a0.x; v[1]=a0.y; v[2]=a0.z; v[3]=a0.w;
      v[4]=a1.x; v[5]=a1.y; v[6]=a1.z; v[7]=a1.w;
    } else {
      bf16x8 u = *((const bf16x8*)s0 + g8);
      #pragma unroll
      for(int j=0;j<8;j++) v[j] = us2f((us)u[j]);
    }
    *(float4*)&ws[O_XF+e0]   = (float4){v[0],v[1],v[2],v[3]};
    *(float4*)&ws[O_XF+e0+4] = (float4){v[4],v[5],v[6],v[7]};
    union{ us a[8]; uint4 q; } hh, ll;
    #pragma unroll
    for(int j=0;j<8;j++){
      us hb = f2bf_rne(v[j]);
      hh.a[j] = hb;
      ll.a[j] = f2bf_rne(v[j] - us2f(hb));
    }
    size_t xi = xhl_idx(e0>>8, e0&255);  // contiguous for j=0..7
    *(uint4*)&((us*)(ws+O_XH))[xi] = hh.q;
    *(uint4*)&((us*)(ws+O_XL))[xi] = ll.q;
    return;
  }
  int g = (b2-512)*256 + threadIdx.x;
  if(g < 4096){ ws[O_MASK+g] = conv1(s1, g, flag)*L2E; return; }
  g -= 4096;
  if(g < 1024){ ws[O_B1+g] = conv1(sb1, g, flag); return; }
  g -= 1024;
  if(g < 512){ ws[O_B2+g] = conv1(sb2, g, flag); return; }
  g -= 512;
  if(g < 4){ ws[O_GM+g] = conv1(sgm, g, flag); return; }
  g -= 4;
  if(g < 4){ ws[O_BT+g] = conv1(sbt, g, flag); return; }
}

// QKV GEMM, v10: REGISTER-DIRECT barrier-free K-loop.
// MODE 2 is dead since R4 (FFN fused), so this kernel is QKV-only.  A (XH/XL)
// is already frag-major in global; B comes from frag-major prep -- both are
// direct bf16x8 loads at exactly the addresses gl_lds16 used to stage (the
// LDS relay's only value was x2 multicast of L2-resident data; latency, not
// L2 BW, is the constraint).  Depth-3 register pipeline (3 sets x 8 bf16x8 =
// 96 VGPR), set index = kc%3 (literal after unroll).  waves_per_eu(3,3) pins
// the allocator's budget at ~168 VGPR (768 blocks = 3 blocks/CU = 3 waves/EU
// natural co-residency) -- the R12-proven pinning lever.  setprio(1) around
// each 12-MFMA cluster (barrier-free -> role diversity, R14-validated).
// Epilogue (LDS transpose + coalesced frag-major stores) unchanged.
// Falsifiers: VGPR~52 = sunk loads; LDS stays 18KB; total >= 226 -> revert.
__global__ void
__launch_bounds__(256)
__attribute__((amdgpu_waves_per_eu(3, 3)))
gemm_qkv(const us* __restrict__ Axh, const us* __restrict__ Axl,
         const us* __restrict__ Bh, const us* __restrict__ Bl,
         us* __restrict__ QH, us* __restrict__ QL,
         us* __restrict__ KH, us* __restrict__ KL, us* __restrict__ VT)
{
  __shared__ __align__(16) us TH[4608], TL[4608];   // 64*72 epilogue transpose
  const int t = threadIdx.x;
  const int w = t>>6, lane = t&63;
  const int Q = lane>>4, L15 = lane&15;
  const int bx = blockIdx.x, by = blockIdx.y;
  const int row0 = bx*64;
  const int nc0 = by*4;
  const int col0 = by*64;

  f32x4 acc[2][2];
  #pragma unroll
  for(int i=0;i<2;i++)
    #pragma unroll
    for(int j=0;j<2;j++) acc[i][j] = (f32x4){0.f,0.f,0.f,0.f};

  // depth-3 register pipeline: full per-step operand state per set
  bf16x8 Ah_[3][2], Al_[3][2], Bh_[3][2], Bl_[3][2];
  auto loadS = [&](int kc, int set){
    size_t abase = ((size_t)(bx*8 + kc))*2048;
    #pragma unroll
    for(int rg2=0;rg2<2;rg2++){
      size_t ai = abase + (size_t)((w&1)*2+rg2)*512 + (size_t)lane*8;
      Ah_[set][rg2] = *(const bf16x8*)&Axh[ai];
      Al_[set][rg2] = *(const bf16x8*)&Axl[ai];
    }
    #pragma unroll
    for(int cg2=0;cg2<2;cg2++){
      size_t bi = ((size_t)(kc*48 + nc0 + (w>>1)*2+cg2)*64 + lane)*8;
      Bh_[set][cg2] = *(const bf16x8*)&Bh[bi];
      Bl_[set][cg2] = *(const bf16x8*)&Bl[bi];
    }
  };

  loadS(0,0); loadS(1,1); loadS(2,2);
  #pragma unroll
  for(int kc=0; kc<8; kc++){
    const int s = kc%3;                    // literal after full unroll
    __builtin_amdgcn_s_setprio(1);
    #pragma unroll
    for(int rg2=0;rg2<2;rg2++)
      #pragma unroll
      for(int cg2=0;cg2<2;cg2++){
        acc[rg2][cg2] = MF(Al_[s][rg2], Bh_[s][cg2], acc[rg2][cg2]);
        acc[rg2][cg2] = MF(Ah_[s][rg2], Bl_[s][cg2], acc[rg2][cg2]);
        acc[rg2][cg2] = MF(Ah_[s][rg2], Bh_[s][cg2], acc[rg2][cg2]);
      }
    __builtin_amdgcn_s_setprio(0);
    if(kc+3 < 8) loadS(kc+3, s);
  }

  // epilogue: LDS transpose + frag-major coalesced stores (unchanged)
  #pragma unroll
  for(int rg2=0;rg2<2;rg2++)
    #pragma unroll
    for(int cg2=0;cg2<2;cg2++)
      #pragma unroll
      for(int r=0;r<4;r++){
        int rl = (w&1)*32 + rg2*16 + Q*4 + r;
        int cl = (w>>1)*32 + cg2*16 + L15;
        float va = acc[rg2][cg2][r];
        us hb = f2bf_rne(va);
        TH[rl*72+cl] = hb;
        TL[rl*72+cl] = f2bf_rne(va - us2f(hb));
      }
  __syncthreads();
  const int sec = col0>>8;
  const int h0  = (col0&255)>>5;
  const int b_  = row0>>11;
  const int srow0 = row0 & 2047;
  if(sec < 2){
    us* DH = (sec==0) ? QH : KH;
    us* DL = (sec==0) ? QL : KL;
    #pragma unroll
    for(int u2=0; u2<2; u2++){
      int u = w + u2*4;
      int rg = u&3, half = u>>2;
      int lbase = (rg*16 + L15)*72 + half*32 + Q*8;
      bf16x8 hv = *(const bf16x8*)&TH[lbase];
      bf16x8 lv = *(const bf16x8*)&TL[lbase];
      int bh = b_*NH + h0 + half;
      size_t dbase = ((size_t)(bh*128 + (srow0>>4) + rg)*64 + lane)*8;
      *(bf16x8*)&DH[dbase] = hv;
      *(bf16x8*)&DL[dbase] = lv;
    }
  } else {
    #pragma unroll
    for(int u2=0; u2<2; u2++){
      int u = w + u2*4;
      int sgrp = u&1, kqh = (u>>1)&1, half = u>>2;
      union{ us u8[8]; bf16x8 v; } vv;
      #pragma unroll
      for(int j=0;j<8;j++){
        int rl = sgrp*32 + Q*8 + j;
        int cl = half*32 + kqh*16 + L15;
        vv.u8[j] = TH[rl*72+cl];
      }
      int bh = b_*NH + h0 + half;
      size_t dbase = ((size_t)((bh*64 + (srow0>>5) + sgrp)*2 + kqh)*64 + lane)*8;
      *(bf16x8*)&VT[dbase] = vv.v;
    }
  }
}

// Fused attn-out + LN + FFN + LN, v9 = depth-8 pipeline + T5 setprio.
// (R14 keeper: barrier-free K-loops + waves_per_eu(2,2) pinning + continuous
// refill across phase seams + setprio on MFMA clusters.)
__global__ void
__launch_bounds__(512)
__attribute__((amdgpu_waves_per_eu(2, 2)))
oln_ffn(const float* __restrict__ OpartA, const float* __restrict__ MLA,
        const us* __restrict__ WOh, const us* __restrict__ WOl,
        const us* __restrict__ W1h, const us* __restrict__ W1l,
        const us* __restrict__ W2h, const us* __restrict__ W2l,
        const float* __restrict__ b1, const float* __restrict__ b2,
        float* __restrict__ xf, us* __restrict__ xh, us* __restrict__ xl,
        const float* __restrict__ gamma, const float* __restrict__ beta, int gi0,
        void* __restrict__ out, int write_out, const int* __restrict__ flagp)
{
  __shared__ __align__(16) us xAH[4096], xAL[4096]; // post-attn-LN x A-frags (8 units)
  __shared__ __align__(16) us hAH[8192], hAL[8192]; // h A-frags (16 units)
  __shared__ float lred[256];                        // 8 waves x 16 rows x {s,sq}
  const int t = threadIdx.x;
  const int w = t>>6, lane = t&63;
  const int Q = lane>>4, L15 = lane&15;
  const int row0 = blockIdx.x*16;
  const int b_ = row0>>11, s0_ = row0&2047;

  // ---- pipelined register state: 8 weight sets x 2 units (128 VGPR) ----
  bf16x8 Wh[8][2], Wl[8][2];
  float4 Ar[2][4];               // 2 A-raw sets x 4 float4
  float  Ml[2][2];

  auto loadWO_ = [&](int kc, int set){
    #pragma unroll
    for(int cg=0;cg<2;cg++){
      size_t fi = (size_t)(kc*16 + w*2 + cg)*512 + (size_t)lane*8;
      Wh[set][cg] = *(const bf16x8*)&WOh[fi];
      Wl[set][cg] = *(const bf16x8*)&WOl[fi];
    }
  };
  auto loadW1_ = [&](int nch, int kc, int set){
    #pragma unroll
    for(int cg=0;cg<2;cg++){
      size_t fi = (size_t)(kc*32 + nch*16 + w*2 + cg)*512 + (size_t)lane*8;
      Wh[set][cg] = *(const bf16x8*)&W1h[fi];
      Wl[set][cg] = *(const bf16x8*)&W1l[fi];
    }
  };
  auto loadW2_ = [&](int kc, int set){
    #pragma unroll
    for(int cg=0;cg<2;cg++){
      size_t fi = (size_t)(kc*16 + w*2 + cg)*512 + (size_t)lane*8;
      Wh[set][cg] = *(const bf16x8*)&W2h[fi];
      Wl[set][cg] = *(const bf16x8*)&W2l[fi];
    }
  };
  auto loadAr = [&](int kc, int set){
    size_t i0 = ((size_t)(b_*8+kc))*2048 + s0_ + L15;
    Ml[set][0] = MLA[i0]; Ml[set][1] = MLA[i0+32768];
    const float* p0 = &OpartA[i0*32 + Q*8];
    const float* p1 = &OpartA[(i0+32768)*32 + Q*8];
    Ar[set][0] = *(const float4*)p0; Ar[set][1] = *(const float4*)(p0+4);
    Ar[set][2] = *(const float4*)p1; Ar[set][3] = *(const float4*)(p1+4);
  };

  // ---------------- phase A: attn-out @ Wo (8 steps, depth-8 pipeline) ----------------
  f32x4 accA[2];
  accA[0] = accA[1] = (f32x4){0.f,0.f,0.f,0.f};

  auto stepA = [&](int aset, int wset){
    float inv = 1.f/(Ml[aset][0] + Ml[aset][1]);
    float fv[8];
    fv[0]=(Ar[aset][0].x+Ar[aset][2].x)*inv; fv[1]=(Ar[aset][0].y+Ar[aset][2].y)*inv;
    fv[2]=(Ar[aset][0].z+Ar[aset][2].z)*inv; fv[3]=(Ar[aset][0].w+Ar[aset][2].w)*inv;
    fv[4]=(Ar[aset][1].x+Ar[aset][3].x)*inv; fv[5]=(Ar[aset][1].y+Ar[aset][3].y)*inv;
    fv[6]=(Ar[aset][1].z+Ar[aset][3].z)*inv; fv[7]=(Ar[aset][1].w+Ar[aset][3].w)*inv;
    union{ us a[8]; bf16x8 v; } Ah_, Al_;
    #pragma unroll
    for(int j=0;j<8;j++){
      us hb = f2bf_rne(fv[j]);
      Ah_.a[j] = hb;
      Al_.a[j] = f2bf_rne(fv[j] - us2f(hb));
    }
    __builtin_amdgcn_s_setprio(1);
    accA[0] = MF(Al_.v, Wh[wset][0], accA[0]);
    accA[0] = MF(Ah_.v, Wl[wset][0], accA[0]);
    accA[0] = MF(Ah_.v, Wh[wset][0], accA[0]);
    accA[1] = MF(Al_.v, Wh[wset][1], accA[1]);
    accA[1] = MF(Ah_.v, Wl[wset][1], accA[1]);
    accA[1] = MF(Ah_.v, Wh[wset][1], accA[1]);
    __builtin_amdgcn_s_setprio(0);
  };

  loadAr(0,0); loadAr(1,1);
  loadWO_(0,0); loadWO_(1,1); loadWO_(2,2); loadWO_(3,3);
  loadWO_(4,4); loadWO_(5,5); loadWO_(6,6); loadWO_(7,7);
  #pragma unroll
  for(int kc=0; kc<8; kc+=2){
    stepA(0, kc);
    loadW1_(0, kc, kc);                   // refill set kc with B1-nch0 weights
    if(kc+2<8) loadAr(kc+2, 0);
    stepA(1, kc+1);
    loadW1_(0, kc+1, kc+1);
    if(kc+3<8) loadAr(kc+3, 1);
  }

  // epilogue A: + residual (prev-layer x, global), LN -> val_s regs + xA LDS
  // (B1-nch0 weight loads land under this VALU-heavy section)
  float tmp[2][4];
  #pragma unroll
  for(int cg=0;cg<2;cg++)
    #pragma unroll
    for(int r=0;r<4;r++){
      int row = row0 + Q*4 + r;
      int c = (w*2+cg)*16 + L15;
      tmp[cg][r] = accA[cg][r] + xf[(size_t)row*DD + c];
    }
  float s[4], sq[4];
  #pragma unroll
  for(int r=0;r<4;r++){
    s[r]  = tmp[0][r]+tmp[1][r];
    sq[r] = tmp[0][r]*tmp[0][r]+tmp[1][r]*tmp[1][r];
  }
  #pragma unroll
  for(int off=1; off<16; off<<=1)
    #pragma unroll
    for(int r=0;r<4;r++){
      s[r]  += __shfl_xor(s[r], off);
      sq[r] += __shfl_xor(sq[r], off);
    }
  if(L15==0){
    #pragma unroll
    for(int r=0;r<4;r++){
      int rl = Q*4 + r;
      lred[(w*16 + rl)*2]   = s[r];
      lred[(w*16 + rl)*2+1] = sq[r];
    }
  }
  __syncthreads();
  float val_s[2][4];
  {
    float g = gamma[gi0], bb = beta[gi0];
    float scv[4], mnv[4];
    #pragma unroll
    for(int r=0;r<4;r++){
      int rl = Q*4 + r;
      float S = 0.f, SQ = 0.f;
      #pragma unroll
      for(int wv=0; wv<8; wv++){
        S  += lred[(wv*16+rl)*2];
        SQ += lred[(wv*16+rl)*2+1];
      }
      float mean = S*(1.f/DD);
      float var  = SQ*(1.f/DD) - mean*mean;
      scv[r] = rsqrtf(var+LN_EPS)*g;
      mnv[r] = mean;
    }
    #pragma unroll
    for(int cg=0;cg<2;cg++){
      int c = (w*2+cg)*16 + L15;
      int base = (c>>5)*512 + (((c&31)>>3))*128 + (c&7);
      #pragma unroll
      for(int r=0;r<4;r++){
        float v = (tmp[cg][r]-mnv[r])*scv[r] + bb;
        val_s[cg][r] = v;
        us hb = f2bf_rne(v);
        xAH[base + (Q*4+r)*8] = hb;
        xAL[base + (Q*4+r)*8] = f2bf_rne(v - us2f(hb));
      }
    }
  }
  __syncthreads();                        // xA visible to all waves

  // ---------------- phase B1: h = relu(val@W1 + b1), continuous refill ----------------
  #pragma unroll
  for(int nch=0; nch<2; nch++){
    f32x4 ah[2];
    ah[0] = ah[1] = (f32x4){0.f,0.f,0.f,0.f};
    #pragma unroll
    for(int kc=0; kc<8; kc++){
      bf16x8 aAh = *(const bf16x8*)&xAH[kc*512 + lane*8];
      bf16x8 aAl = *(const bf16x8*)&xAL[kc*512 + lane*8];
      __builtin_amdgcn_s_setprio(1);
      ah[0] = MF(aAl, Wh[kc][0], ah[0]);
      ah[0] = MF(aAh, Wl[kc][0], ah[0]);
      ah[0] = MF(aAh, Wh[kc][0], ah[0]);
      ah[1] = MF(aAl, Wh[kc][1], ah[1]);
      ah[1] = MF(aAh, Wl[kc][1], ah[1]);
      ah[1] = MF(aAh, Wh[kc][1], ah[1]);
      __builtin_amdgcn_s_setprio(0);
      if(nch==0) loadW1_(1, kc, kc);      // refill with nch1 weights
      else       loadW2_(kc, kc);         // refill with B2 steps 0..7
    }
    #pragma unroll
    for(int cg=0;cg<2;cg++){
      int col = nch*256 + (w*2+cg)*16 + L15;
      float bv = b1[col];
      int base = (col>>5)*512 + (((col&31)>>3))*128 + (col&7);
      #pragma unroll
      for(int r=0;r<4;r++){
        int row = Q*4 + r;
        float v = ah[cg][r] + bv;
        v = v>0.f ? v : 0.f;
        us hb = f2bf_rne(v);
        hAH[base + row*8] = hb;
        hAL[base + row*8] = f2bf_rne(v - us2f(hb));
      }
    }
  }
  __syncthreads();                        // hA visible to all waves

  // ---------------- phase B2: y = h@W2 (16 steps, depth-8) ----------------
  f32x4 ay[2];
  ay[0] = ay[1] = (f32x4){0.f,0.f,0.f,0.f};
  #pragma unroll
  for(int kc2=0; kc2<16; kc2++){
    const int sub = kc2 & 7;
    bf16x8 aAh = *(const bf16x8*)&hAH[kc2*512 + lane*8];
    bf16x8 aAl = *(const bf16x8*)&hAL[kc2*512 + lane*8];
    __builtin_amdgcn_s_setprio(1);
    ay[0] = MF(aAl, Wh[sub][0], ay[0]);
    ay[0] = MF(aAh, Wl[sub][0], ay[0]);
    ay[0] = MF(aAh, Wh[sub][0], ay[0]);
    ay[1] = MF(aAl, Wh[sub][1], ay[1]);
    ay[1] = MF(aAh, Wl[sub][1], ay[1]);
    ay[1] = MF(aAh, Wh[sub][1], ay[1]);
    __builtin_amdgcn_s_setprio(0);
    if(kc2+8 < 16) loadW2_(kc2+8, sub);   // refill for steps 8..15
  }

  // ---------------- epilogue B: +b2 +val(res regs), LN, global writes ----------------
  float tmp2[2][4];
  #pragma unroll
  for(int cg=0;cg<2;cg++)
    #pragma unroll
    for(int r=0;r<4;r++){
      int c = (w*2+cg)*16 + L15;
      tmp2[cg][r] = ay[cg][r] + val_s[cg][r] + b2[c];
    }
  float s2[4], sq2[4];
  #pragma unroll
  for(int r=0;r<4;r++){
    s2[r]  = tmp2[0][r]+tmp2[1][r];
    sq2[r] = tmp2[0][r]*tmp2[0][r]+tmp2[1][r]*tmp2[1][r];
  }
  #pragma unroll
  for(int off=1; off<16; off<<=1)
    #pragma unroll
    for(int r=0;r<4;r++){
      s2[r]  += __shfl_xor(s2[r], off);
      sq2[r] += __shfl_xor(sq2[r], off);
    }
  if(L15==0){
    #pragma unroll
    for(int r=0;r<4;r++){
      int rl = Q*4 + r;
      lred[(w*16 + rl)*2]   = s2[r];
      lred[(w*16 + rl)*2+1] = sq2[r];
    }
  }
  __syncthreads();
  float g2 = gamma[gi0+1], bb2 = beta[gi0+1];
  float scv2[4], mnv2[4];
  #pragma unroll
  for(int r=0;r<4;r++){
    int rl = Q*4 + r;
    float S = 0.f, SQ = 0.f;
    #pragma unroll
    for(int wv=0; wv<8; wv++){
      S  += lred[(wv*16+rl)*2];
      SQ += lred[(wv*16+rl)*2+1];
    }
    float mean = S*(1.f/DD);
    float var  = SQ*(1.f/DD) - mean*mean;
    scv2[r] = rsqrtf(var+LN_EPS)*g2;
    mnv2[r] = mean;
  }
  int flag = write_out ? *flagp : 0;
  #pragma unroll
  for(int cg=0;cg<2;cg++)
    #pragma unroll
    for(int r=0;r<4;r++){
      int row = row0 + Q*4 + r;
      int c = (w*2+cg)*16 + L15;
      float val = (tmp2[cg][r]-mnv2[r])*scv2[r] + bb2;
      xf[(size_t)row*DD + c] = val;
      us hb = f2bf_rne(val);
      size_t xi = xhl_idx(row, c);
      xh[xi] = hb;
      xl[xi] = f2bf_rne(val - us2f(hb));
      if(write_out){
        if(flag) ((float*)out)[(size_t)row*DD + c] = val;
        else     ((bf16*)out)[(size_t)row*DD + c] = __float2bfloat16(val);
      }
    }
}

// MFMA flash attention: v9 double-buffer schedule; full 1024-float mask row
// staged ONCE at prologue via one gl_lds16.  T5 s_setprio(1) around MFMA
// clusters (R11: part of the 247.5->239.9 win).
__launch_bounds__(256)
__global__ void attn_kernel(const us* __restrict__ QH, const us* __restrict__ QL,
                            const us* __restrict__ KH, const us* __restrict__ KL,
                            const us* __restrict__ VT,
                            const float* __restrict__ mask,
                            float* __restrict__ Opart, float* __restrict__ ML)
{
  __shared__ __align__(16) us Khs[4096], Kls[4096], Vts[4096];  // 2 bufs x 2048
  __shared__ __align__(16) float Msl[1024];                      // full ks-half mask
  const int t = threadIdx.x;
  const int bh = blockIdx.x >> 6;
  const int qt = (blockIdx.x & 63) >> 1;
  const int ks = blockIdx.x & 1;
  const int b_ = bh >> 3;
  const int wv = t >> 6;
  const int lane = t & 63;
  const int Q = lane >> 4, L15 = lane & 15;
  const int q0 = qt*64 + wv*16;

  size_t qidx = ((size_t)(bh*128 + qt*4 + wv)*64 + lane)*8;
  const bf16x8 qh_v = *(const bf16x8*)&QH[qidx];
  const bf16x8 ql_v = *(const bf16x8*)&QL[qidx];

  const us* KHbh = KH + (size_t)bh*65536;
  const us* KLbh = KL + (size_t)bh*65536;
  const us* VTbh = VT + (size_t)bh*65536;
  const int base = ks*1024;

  f32x4 Oa0a = {0.f,0.f,0.f,0.f}, Oa0b = {0.f,0.f,0.f,0.f};
  f32x4 Oa1a = {0.f,0.f,0.f,0.f}, Oa1b = {0.f,0.f,0.f,0.f};
  float lacc = 0.f;

  // prologue: mask row (1 async op) + stage 0 into buffer 0
  {
    const us* mrow = (const us*)(mask + (size_t)b_*SS + base);
    gl_lds16(mrow + (size_t)t*8, ((us*)Msl) + t*8);
    size_t kbase = (size_t)(base>>4)*512;
    size_t vbase = (size_t)(base>>5)*1024;
    gl_lds16(&KHbh[kbase + (size_t)t*8], &Khs[t*8]);
    gl_lds16(&KLbh[kbase + (size_t)t*8], &Kls[t*8]);
    gl_lds16(&VTbh[vbase + (size_t)t*8], &Vts[t*8]);
  }

  for(int s=0; s<16; s++){
    __syncthreads();                         // drains loads(s); orders buffer reuse
    if(s < 15){
      int t0n = base + (s+1)*64;
      int bn = (s+1)&1;
      size_t kbase = (size_t)(t0n>>4)*512;
      size_t vbase = (size_t)(t0n>>5)*1024;
      gl_lds16(&KHbh[kbase + (size_t)t*8], &Khs[bn*2048 + t*8]);
      gl_lds16(&KLbh[kbase + (size_t)t*8], &Kls[bn*2048 + t*8]);
      gl_lds16(&VTbh[vbase + (size_t)t*8], &Vts[bn*2048 + t*8]);
    }
    const int bo = (s&1)*2048;
    const int mo = s*64;

    // QK^T -> S^T (3 MFMAs per 16-key tile, 4 tiles)
    f32x4 St[4];
    const f32x4 zz = {0.f,0.f,0.f,0.f};
    __builtin_amdgcn_s_setprio(1);
    #pragma unroll
    for(int kt=0;kt<4;kt++){
      bf16x8 aKh = *(const bf16x8*)&Khs[bo + kt*512 + lane*8];
      bf16x8 aKl = *(const bf16x8*)&Kls[bo + kt*512 + lane*8];
      f32x4 a = MF(aKl, qh_v, zz);
      a = MF(aKh, ql_v, a);
      a = MF(aKh, qh_v, a);
      St[kt] = a;
    }
    __builtin_amdgcn_s_setprio(0);

    // fixed-shift softmax in log2 space
    float lsum = 0.f;
    #pragma unroll
    for(int kt=0;kt<4;kt++){
      float4 mv = *(const float4*)&Msl[mo + kt*16 + Q*4];
      float mvr[4] = {mv.x, mv.y, mv.z, mv.w};
      #pragma unroll
      for(int r=0;r<4;r++){
        float p = EXP2F(fmaf(mvr[r], St[kt][r], -SOFT_SHIFT_L2E));
        St[kt][r] = p;
        lsum += p;
      }
    }
    lacc += lsum;

    // pack P -> bf16 pairs
    int pk[4][2];
    #pragma unroll
    for(int kt=0;kt<4;kt++){
      pk[kt][0] = pack_bf16(St[kt][0], St[kt][1]);
      pk[kt][1] = pack_bf16(St[kt][2], St[kt][3]);
    }

    // PV: O^T += V^T · P^T (2 chunks of 32 keys; c0 -> a regs, c1 -> b regs)
    #pragma unroll
    for(int c=0;c<2;c++){
      union { int i[4]; bf16x8 v; } bu;
      #pragma unroll
      for(int d=0;d<4;d++){
        int srcl = (((Q&1)*2 + (d>>1))<<4) | L15;
        int vlo = __shfl(pk[2*c  ][d&1], srcl, 64);
        int vhi = __shfl(pk[2*c+1][d&1], srcl, 64);
        bu.i[d] = (Q & 2) ? vhi : vlo;
      }
      bf16x8 aV0 = *(const bf16x8*)&Vts[bo + (c*2+0)*512 + lane*8];
      bf16x8 aV1 = *(const bf16x8*)&Vts[bo + (c*2+1)*512 + lane*8];
      __builtin_amdgcn_s_setprio(1);
      if(c == 0){
        Oa0a = MF(aV0, bu.v, Oa0a);
        Oa1a = MF(aV1, bu.v, Oa1a);
      } else {
        Oa0b = MF(aV0, bu.v, Oa0b);
        Oa1b = MF(aV1, bu.v, Oa1b);
      }
      __builtin_amdgcn_s_setprio(0);
    }
  }

  f32x4 Oa0 = Oa0a + Oa0b;
  f32x4 Oa1 = Oa1a + Oa1b;
  lacc += __shfl_xor(lacc, 16);
  lacc += __shfl_xor(lacc, 32);

  float* opp = &Opart[((size_t)(ks*16+bh)*SS + q0 + L15)*32];
  #pragma unroll
  for(int r=0;r<4;r++){
    opp[Q*4+r]    = Oa0[r];
    opp[16+Q*4+r] = Oa1[r];
  }
  if(Q==0){
    ML[(size_t)(ks*16+bh)*SS + q0 + L15] = lacc;
  }
}

extern "C" void kernel_launch(void* const* d_in, const int* in_sizes, int n_in,
                              void* d_out, int out_size, void* d_ws, size_t ws_size,
                              hipStream_t stream)
{
  float* ws = (float*)d_ws;
  int* flagp = (int*)d_ws;

  float* xf  = ws + O_XF;
  us* QHb = (us*)(ws + O_QB);
  us* QLb = QHb + 1048576;
  us* KH = (us*)(ws + O_KH);
  us* KL = (us*)(ws + O_KL);
  us* VT = (us*)(ws + O_VT);
  us* XH = (us*)(ws + O_XH);
  us* XL = (us*)(ws + O_XL);
  float* Opart = ws + O_OP;
  float* ML  = ws + O_ML;
  float* b1f = ws + O_B1;
  float* b2f_ = ws + O_B2;
  float* gmf = ws + O_GM;
  float* btf = ws + O_BT;
  us* prep = (us*)(ws + O_PREP);

  conv_prep<<<PREP_BLOCKS+CONV_BLOCKS,256,0,stream>>>(
      d_in[0], d_in[1], d_in[2], d_in[3], d_in[4], d_in[5],
      d_in[6], d_in[7], d_in[8], d_in[9], d_in[10], d_in[11],
      ws, flagp);

  for(int i=0;i<NL;i++){
    const float* b1i = b1f + (size_t)i*DFF;
    const float* b2i = b2f_ + (size_t)i*DD;

    dim3 g0(64, 12);
    gemm_qkv<<<g0,256,0,stream>>>(XH, XL,
                                  prep+PQH+(size_t)i*196608, prep+PQL+(size_t)i*196608,
                                  QHb, QLb, KH, KL, VT);
    attn_kernel<<<1024,256,0,stream>>>(QHb, QLb, KH, KL, VT, ws + O_MASK, Opart, ML);
    oln_ffn<<<256,512,0,stream>>>(Opart, ML,
                                  prep+POH+(size_t)i*65536, prep+POL+(size_t)i*65536,
                                  prep+P1H+(size_t)i*131072, prep+P1L+(size_t)i*131072,
                                  prep+P2H+(size_t)i*131072, prep+P2L+(size_t)i*131072,
                                  b1i, b2i, xf, XH, XL,
                                  gmf, btf, 2*i, d_out, (i==NL-1)?1:0, flagp);
  }
}

// Round 16
// 223.505 us; speedup vs baseline: 1.0176x; 1.0176x over previous
//
#include <hip/hip_runtime.h>
#include <hip/hip_bf16.h>

#define NL 2
#define NH 8
#define DKk 32
#define DVv 32
#define DFF 512
#define DD 256
#define BB 2
#define SS 2048
#define MROWS (BB*SS)            // 4096
#define LN_EPS 1e-14f
#define L2E 1.4426950408889634f
#define SOFT_SHIFT_L2E (50.0f*L2E)   // fixed softmax shift, in log2 units

typedef __hip_bfloat16 bf16;
typedef unsigned short us;
typedef short bf16x8 __attribute__((ext_vector_type(8)));   // 8 bf16 = 4 VGPRs
typedef float f32x4  __attribute__((ext_vector_type(4)));
typedef unsigned short us4 __attribute__((ext_vector_type(4)));

// ---- workspace layout (floats) ----
#define O_XF   256
#define O_QB   (O_XF+1048576)      // QH (1048576 us) + QL (1048576 us) frag-major
#define O_KH   (O_QB+1048576)
#define O_KL   (O_KH+524288)
#define O_VT   (O_KL+524288)
#define O_XH   (O_VT+524288)       // x pre-split hi (1048576 us)
#define O_XL   (O_XH+524288)       // x pre-split lo
#define O_OP   (O_XL+524288)       // 2097152: key-split x2 partial O
#define O_ML   (O_OP+2097152)      // 65536: key-split l (m is constant)
#define O_MASK (O_ML+65536)
#define O_B1   (O_MASK+4096)
#define O_B2   (O_B1+1024)
#define O_GM   (O_B2+512)
#define O_BT   (O_GM+4)
#define O_PREP (O_BT+4)
// conv: x handled 8-wide by 512 blocks; tail segments (mask|b1|b2|gamma|beta)
#define TAIL_TOTAL (4096+1024+512+4+4)
#define CONV_BLOCKS (512 + (TAIL_TOTAL+255)/256)
#define PREP_BLOCKS 512
// prep region offsets in ushorts (relative to (us*)(ws+O_PREP))
#define PQH 0u
#define PQL 393216u
#define POH 786432u
#define POL 917504u
#define P1H 1048576u
#define P1L 1310720u
#define P2H 1572864u
#define P2L 1835008u

__device__ __forceinline__ float us2f(us u){
  unsigned int v = ((unsigned int)u) << 16; float f;
  __builtin_memcpy(&f, &v, 4); return f;
}
__device__ __forceinline__ us f2bf_rne(float f){
  unsigned int b = __float_as_uint(f);
  b += 0x7FFFu + ((b>>16)&1u);
  return (us)(b>>16);
}

#if __has_builtin(__builtin_amdgcn_exp2f)
#define EXP2F(x) __builtin_amdgcn_exp2f(x)
#else
#define EXP2F(x) exp2f(x)
#endif

#if __has_builtin(__builtin_amdgcn_cvt_pk_bf16_f32)
typedef __bf16 bf16x2_t __attribute__((ext_vector_type(2)));
__device__ __forceinline__ int pack_bf16(float a, float b){
  bf16x2_t r = __builtin_amdgcn_cvt_pk_bf16_f32(a, b);
  int i; __builtin_memcpy(&i, &r, 4); return i;
}
#else
__device__ __forceinline__ int pack_bf16(float a, float b){
  int b0 = __float_as_int(a) + 0x8000;
  int b1 = __float_as_int(b) + 0x8000;
  return (b1 & 0xFFFF0000) | ((int)((unsigned)b0 >> 16));
}
#endif

__device__ __forceinline__ f32x4 MF(bf16x8 a, bf16x8 b, f32x4 c){
  return __builtin_amdgcn_mfma_f32_16x16x32_bf16(a,b,c,0,0,0);
}

// Async global->LDS 16B copy (lane-linear layouts only).
__device__ __forceinline__ void gl_lds16(const us* g, us* l){
  __builtin_amdgcn_global_load_lds(
    (const __attribute__((address_space(1))) unsigned int*)g,
    (__attribute__((address_space(3))) unsigned int*)l, 16, 0, 0);
}

// x pre-split frag-major index for element (row, col), K=256 tiling.
__device__ __forceinline__ size_t xhl_idx(int row, int col){
  int rt = row>>6, rg = (row>>4)&3, L15 = row&15;
  int kc = col>>5, Q = (col>>3)&3, j = col&7;
  return ((size_t)(rt*8+kc))*2048 + rg*512 + Q*128 + L15*8 + j;
}

__device__ __forceinline__ float conv1(const void* src, size_t i, int flag){
  if(flag) return ((const float*)src)[i];
  return us2f(((const us*)src)[i]);
}

// Build fragment-major hi/lo bf16 B-operands reading RAW (flag-dtype) weights.
__device__ __forceinline__ void prep_b_raw(const void* W0, const void* W1v, const void* W2v,
                                           int baseoff, us* __restrict__ Bh, us* __restrict__ Bl,
                                           int Kd, int Nd, int qkv, int g, int flag)
{
  int total = (Kd/32)*(Nd/16)*64;
  if(g >= total) return;
  int lane = g & 63, fi = g >> 6;
  int ncN = Nd/16;
  int nc = fi % ncN, kc = fi / ncN;
  int Q = lane>>4, L15 = lane&15;
  int n = nc*16 + L15;
  const void* src;
  int off0, stride;
  if(qkv){
    int sec = n>>8, h = (n>>5)&7, kq = n&31;
    src = (sec==0)?W0:((sec==1)?W1v:W2v);
    off0 = baseoff + h*8192 + kq;
    stride = 32;
  } else {
    src = W0;
    off0 = baseoff + n;
    stride = Nd;
  }
  #pragma unroll
  for(int j=0;j<8;j++){
    int k = kc*32 + Q*8 + j;
    float v = conv1(src, (size_t)off0 + (size_t)k*stride, flag);
    us hb = f2bf_rne(v);
    Bh[(size_t)g*8 + j] = hb;
    Bl[(size_t)g*8 + j] = f2bf_rne(v - us2f(hb));
  }
}

// Fused: dtype-detect (per-block) + weight prep (blocks 0..511) + input conversion.
// x conversion is 8-wide per thread (16B loads, 16B frag-major stores).
__global__ void conv_prep(const void* s0, const void* s1, const void* sWq, const void* sWk,
                          const void* sWv, const void* sWo, const void* sW1, const void* sb1,
                          const void* sW2, const void* sb2, const void* sgm, const void* sbt,
                          float* __restrict__ ws, int* __restrict__ flagp)
{
  __shared__ int fsh[4];
  int bad = 0;
  const us* xr = (const us*)s0;
  for(int i=threadIdx.x; i<4096; i+=256){
    float f = us2f(xr[i]);
    if(!(fabsf(f) < 1e3f)) bad = 1;
  }
  unsigned long long m = __ballot(bad);
  if((threadIdx.x&63)==0) fsh[threadIdx.x>>6] = (m!=0ull);
  __syncthreads();
  int flag = (fsh[0]|fsh[1]|fsh[2]|fsh[3]);
  if(blockIdx.x==0 && threadIdx.x==0) *flagp = flag;

  int b = blockIdx.x;
  if(b < PREP_BLOCKS){
    int layer = b >> 8, lb = b & 255;
    us* prep = (us*)(ws + O_PREP);
    if(lb < 96){
      int g = lb*256 + threadIdx.x;
      prep_b_raw(sWq, sWk, sWv, layer*65536, prep+PQH+(size_t)layer*196608,
                 prep+PQL+(size_t)layer*196608, 256, 768, 1, g, flag);
    } else if(lb < 128){
      int g = (lb-96)*256 + threadIdx.x;
      prep_b_raw(sWo, nullptr, nullptr, layer*65536, prep+POH+(size_t)layer*65536,
                 prep+POL+(size_t)layer*65536, 256, 256, 0, g, flag);
    } else if(lb < 192){
      int g = (lb-128)*256 + threadIdx.x;
      prep_b_raw(sW1, nullptr, nullptr, layer*131072, prep+P1H+(size_t)layer*131072,
                 prep+P1L+(size_t)layer*131072, 256, 512, 0, g, flag);
    } else {
      int g = (lb-192)*256 + threadIdx.x;
      prep_b_raw(sW2, nullptr, nullptr, layer*131072, prep+P2H+(size_t)layer*131072,
                 prep+P2L+(size_t)layer*131072, 512, 256, 0, g, flag);
    }
    return;
  }
  int b2 = b - PREP_BLOCKS;
  if(b2 < 512){
    // x: 8 consecutive elements per thread (one row, 8-aligned col block).
    int g8 = b2*256 + threadIdx.x;       // 0..131071
    int e0 = g8*8;
    float v[8];
    if(flag){
      float4 a0 = *((const float4*)s0 + (e0>>2));
      float4 a1 = *((const float4*)s0 + (e0>>2) + 1);
      v[0]=a0.x; v[1]=a0.y; v[2]=a0.z; v[3]=a0.w;
      v[4]=a1.x; v[5]=a1.y; v[6]=a1.z; v[7]=a1.w;
    } else {
      bf16x8 u = *((const bf16x8*)s0 + g8);
      #pragma unroll
      for(int j=0;j<8;j++) v[j] = us2f((us)u[j]);
    }
    *(float4*)&ws[O_XF+e0]   = (float4){v[0],v[1],v[2],v[3]};
    *(float4*)&ws[O_XF+e0+4] = (float4){v[4],v[5],v[6],v[7]};
    union{ us a[8]; uint4 q; } hh, ll;
    #pragma unroll
    for(int j=0;j<8;j++){
      us hb = f2bf_rne(v[j]);
      hh.a[j] = hb;
      ll.a[j] = f2bf_rne(v[j] - us2f(hb));
    }
    size_t xi = xhl_idx(e0>>8, e0&255);  // contiguous for j=0..7
    *(uint4*)&((us*)(ws+O_XH))[xi] = hh.q;
    *(uint4*)&((us*)(ws+O_XL))[xi] = ll.q;
    return;
  }
  int g = (b2-512)*256 + threadIdx.x;
  if(g < 4096){ ws[O_MASK+g] = conv1(s1, g, flag)*L2E; return; }
  g -= 4096;
  if(g < 1024){ ws[O_B1+g] = conv1(sb1, g, flag); return; }
  g -= 1024;
  if(g < 512){ ws[O_B2+g] = conv1(sb2, g, flag); return; }
  g -= 512;
  if(g < 4){ ws[O_GM+g] = conv1(sgm, g, flag); return; }
  g -= 4;
  if(g < 4){ ws[O_BT+g] = conv1(sbt, g, flag); return; }
}

// Split-bf16 MFMA QKV GEMM (64x64 tile, 4 waves, 3 MFMAs/frag/K32), A pre-split.
// v9 schedule (R14 keeper; R15's register-direct variant regressed — at 3
// blocks/CU the inter-block TLP already hides the barrier drain, and the LDS
// relay's x2 multicast halves L2 requests): double-buffered LDS, 1
// __syncthreads per K-step, stage(kc+1) right after the barrier.
// QKV -> QH/QL, KH/KL, VT frag-major via LDS-transposed COALESCED stores.
template<int MODE>
__launch_bounds__(256)
__global__ void gemm_mfma(const us* __restrict__ Axh, const us* __restrict__ Axl,
                          const us* __restrict__ Bh, const us* __restrict__ Bl,
                          const float* __restrict__ bias,
                          float* __restrict__ O,
                          us* __restrict__ QH, us* __restrict__ QL,
                          us* __restrict__ KH, us* __restrict__ KL, us* __restrict__ VT,
                          int Ncols, int Kdim)
{
  // 2 bufs x (Ah|Al|Bhs|Bls x 2048 us) = 16384 us = 32 KB; epi TH/TL (9216 us) aliases
  __shared__ __align__(16) us SH[16384];
  const int t = threadIdx.x;
  const int w = t>>6, lane = t&63;
  const int Q = lane>>4, L15 = lane&15;
  const int bx = blockIdx.x, by = blockIdx.y;
  const int row0 = bx*64;
  const int nc0 = by*4;
  const int col0 = by*64;
  const int nKc = Kdim>>5;
  const int ncW = Ncols>>4;

  f32x4 acc[2][2];
  #pragma unroll
  for(int i=0;i<2;i++)
    #pragma unroll
    for(int j=0;j<2;j++) acc[i][j] = (f32x4){0.f,0.f,0.f,0.f};

  auto stage = [&](int kc){
    const int bo = (kc&1)*8192;
    size_t abase = ((size_t)(bx*nKc + kc))*2048;
    gl_lds16(&Axh[abase + (size_t)t*8], &SH[bo + t*8]);
    gl_lds16(&Axl[abase + (size_t)t*8], &SH[bo + 2048 + t*8]);
    size_t gidx = ((size_t)(kc*ncW + nc0 + w)*64 + lane)*8;
    gl_lds16(&Bh[gidx], &SH[bo + 4096 + t*8]);
    gl_lds16(&Bl[gidx], &SH[bo + 6144 + t*8]);
  };

  // prologue: stage kc=0 into buffer 0
  stage(0);

  for(int kc=0; kc<nKc; kc++){
    __syncthreads();                      // drains loads(kc); orders buffer reuse
    if(kc+1 < nKc) stage(kc+1);
    const int bo = (kc&1)*8192;
    const us* Ah  = SH + bo;
    const us* Al  = SH + bo + 2048;
    const us* Bhs = SH + bo + 4096;
    const us* Bls = SH + bo + 6144;

    bf16x8 aAh[2], aAl[2], bBh[2], bBl[2];
    #pragma unroll
    for(int rg2=0;rg2<2;rg2++){
      int rg = (w&1)*2 + rg2;
      aAh[rg2] = *(const bf16x8*)&Ah[rg*512 + lane*8];
      aAl[rg2] = *(const bf16x8*)&Al[rg*512 + lane*8];
    }
    #pragma unroll
    for(int cg2=0;cg2<2;cg2++){
      int nc = (w>>1)*2 + cg2;
      bBh[cg2] = *(const bf16x8*)&Bhs[nc*512 + lane*8];
      bBl[cg2] = *(const bf16x8*)&Bls[nc*512 + lane*8];
    }
    #pragma unroll
    for(int rg2=0;rg2<2;rg2++)
      #pragma unroll
      for(int cg2=0;cg2<2;cg2++){
        acc[rg2][cg2] = MF(aAl[rg2], bBh[cg2], acc[rg2][cg2]);
        acc[rg2][cg2] = MF(aAh[rg2], bBl[cg2], acc[rg2][cg2]);
        acc[rg2][cg2] = MF(aAh[rg2], bBh[cg2], acc[rg2][cg2]);
      }
  }

  if(MODE==0){
    __syncthreads();                      // all frag reads done before TH/TL alias
    us* TH = SH;          // 64*72 = 4608 us
    us* TL = SH + 4608;
    #pragma unroll
    for(int rg2=0;rg2<2;rg2++)
      #pragma unroll
      for(int cg2=0;cg2<2;cg2++)
        #pragma unroll
        for(int r=0;r<4;r++){
          int rl = (w&1)*32 + rg2*16 + Q*4 + r;
          int cl = (w>>1)*32 + cg2*16 + L15;
          float va = acc[rg2][cg2][r];
          us hb = f2bf_rne(va);
          TH[rl*72+cl] = hb;
          TL[rl*72+cl] = f2bf_rne(va - us2f(hb));
        }
    __syncthreads();
    const int sec = col0>>8;
    const int h0  = (col0&255)>>5;
    const int b_  = row0>>11;
    const int srow0 = row0 & 2047;
    if(sec < 2){
      us* DH = (sec==0) ? QH : KH;
      us* DL = (sec==0) ? QL : KL;
      #pragma unroll
      for(int u2=0; u2<2; u2++){
        int u = w + u2*4;
        int rg = u&3, half = u>>2;
        int lbase = (rg*16 + L15)*72 + half*32 + Q*8;
        bf16x8 hv = *(const bf16x8*)&TH[lbase];
        bf16x8 lv = *(const bf16x8*)&TL[lbase];
        int bh = b_*NH + h0 + half;
        size_t dbase = ((size_t)(bh*128 + (srow0>>4) + rg)*64 + lane)*8;
        *(bf16x8*)&DH[dbase] = hv;
        *(bf16x8*)&DL[dbase] = lv;
      }
    } else {
      #pragma unroll
      for(int u2=0; u2<2; u2++){
        int u = w + u2*4;
        int sgrp = u&1, kqh = (u>>1)&1, half = u>>2;
        union{ us u8[8]; bf16x8 v; } vv;
        #pragma unroll
        for(int j=0;j<8;j++){
          int rl = sgrp*32 + Q*8 + j;
          int cl = half*32 + kqh*16 + L15;
          vv.u8[j] = TH[rl*72+cl];
        }
        int bh = b_*NH + h0 + half;
        size_t dbase = ((size_t)((bh*64 + (srow0>>5) + sgrp)*2 + kqh)*64 + lane)*8;
        *(bf16x8*)&VT[dbase] = vv.v;
      }
    }
  } else {
    #pragma unroll
    for(int rg2=0;rg2<2;rg2++)
      #pragma unroll
      for(int cg2=0;cg2<2;cg2++)
        #pragma unroll
        for(int r=0;r<4;r++){
          int row = row0 + (w&1)*32 + rg2*16 + Q*4 + r;
          int c   = col0 + (w>>1)*32 + cg2*16 + L15;
          float v = acc[rg2][cg2][r] + bias[c];
          O[(size_t)row*Ncols + c] = v>0.f ? v : 0.f;
        }
  }
}

// Fused attn-out + LN + FFN + LN, v9 = depth-8 pipeline + T5 setprio.
// (R14 keeper: barrier-free K-loops + waves_per_eu(2,2) pinning + continuous
// refill across phase seams + setprio on MFMA clusters.)
__global__ void
__launch_bounds__(512)
__attribute__((amdgpu_waves_per_eu(2, 2)))
oln_ffn(const float* __restrict__ OpartA, const float* __restrict__ MLA,
        const us* __restrict__ WOh, const us* __restrict__ WOl,
        const us* __restrict__ W1h, const us* __restrict__ W1l,
        const us* __restrict__ W2h, const us* __restrict__ W2l,
        const float* __restrict__ b1, const float* __restrict__ b2,
        float* __restrict__ xf, us* __restrict__ xh, us* __restrict__ xl,
        const float* __restrict__ gamma, const float* __restrict__ beta, int gi0,
        void* __restrict__ out, int write_out, const int* __restrict__ flagp)
{
  __shared__ __align__(16) us xAH[4096], xAL[4096]; // post-attn-LN x A-frags (8 units)
  __shared__ __align__(16) us hAH[8192], hAL[8192]; // h A-frags (16 units)
  __shared__ float lred[256];                        // 8 waves x 16 rows x {s,sq}
  const int t = threadIdx.x;
  const int w = t>>6, lane = t&63;
  const int Q = lane>>4, L15 = lane&15;
  const int row0 = blockIdx.x*16;
  const int b_ = row0>>11, s0_ = row0&2047;

  // ---- pipelined register state: 8 weight sets x 2 units (128 VGPR) ----
  bf16x8 Wh[8][2], Wl[8][2];
  float4 Ar[2][4];               // 2 A-raw sets x 4 float4
  float  Ml[2][2];

  auto loadWO_ = [&](int kc, int set){
    #pragma unroll
    for(int cg=0;cg<2;cg++){
      size_t fi = (size_t)(kc*16 + w*2 + cg)*512 + (size_t)lane*8;
      Wh[set][cg] = *(const bf16x8*)&WOh[fi];
      Wl[set][cg] = *(const bf16x8*)&WOl[fi];
    }
  };
  auto loadW1_ = [&](int nch, int kc, int set){
    #pragma unroll
    for(int cg=0;cg<2;cg++){
      size_t fi = (size_t)(kc*32 + nch*16 + w*2 + cg)*512 + (size_t)lane*8;
      Wh[set][cg] = *(const bf16x8*)&W1h[fi];
      Wl[set][cg] = *(const bf16x8*)&W1l[fi];
    }
  };
  auto loadW2_ = [&](int kc, int set){
    #pragma unroll
    for(int cg=0;cg<2;cg++){
      size_t fi = (size_t)(kc*16 + w*2 + cg)*512 + (size_t)lane*8;
      Wh[set][cg] = *(const bf16x8*)&W2h[fi];
      Wl[set][cg] = *(const bf16x8*)&W2l[fi];
    }
  };
  auto loadAr = [&](int kc, int set){
    size_t i0 = ((size_t)(b_*8+kc))*2048 + s0_ + L15;
    Ml[set][0] = MLA[i0]; Ml[set][1] = MLA[i0+32768];
    const float* p0 = &OpartA[i0*32 + Q*8];
    const float* p1 = &OpartA[(i0+32768)*32 + Q*8];
    Ar[set][0] = *(const float4*)p0; Ar[set][1] = *(const float4*)(p0+4);
    Ar[set][2] = *(const float4*)p1; Ar[set][3] = *(const float4*)(p1+4);
  };

  // ---------------- phase A: attn-out @ Wo (8 steps, depth-8 pipeline) ----------------
  f32x4 accA[2];
  accA[0] = accA[1] = (f32x4){0.f,0.f,0.f,0.f};

  auto stepA = [&](int aset, int wset){
    float inv = 1.f/(Ml[aset][0] + Ml[aset][1]);
    float fv[8];
    fv[0]=(Ar[aset][0].x+Ar[aset][2].x)*inv; fv[1]=(Ar[aset][0].y+Ar[aset][2].y)*inv;
    fv[2]=(Ar[aset][0].z+Ar[aset][2].z)*inv; fv[3]=(Ar[aset][0].w+Ar[aset][2].w)*inv;
    fv[4]=(Ar[aset][1].x+Ar[aset][3].x)*inv; fv[5]=(Ar[aset][1].y+Ar[aset][3].y)*inv;
    fv[6]=(Ar[aset][1].z+Ar[aset][3].z)*inv; fv[7]=(Ar[aset][1].w+Ar[aset][3].w)*inv;
    union{ us a[8]; bf16x8 v; } Ah_, Al_;
    #pragma unroll
    for(int j=0;j<8;j++){
      us hb = f2bf_rne(fv[j]);
      Ah_.a[j] = hb;
      Al_.a[j] = f2bf_rne(fv[j] - us2f(hb));
    }
    __builtin_amdgcn_s_setprio(1);
    accA[0] = MF(Al_.v, Wh[wset][0], accA[0]);
    accA[0] = MF(Ah_.v, Wl[wset][0], accA[0]);
    accA[0] = MF(Ah_.v, Wh[wset][0], accA[0]);
    accA[1] = MF(Al_.v, Wh[wset][1], accA[1]);
    accA[1] = MF(Ah_.v, Wl[wset][1], accA[1]);
    accA[1] = MF(Ah_.v, Wh[wset][1], accA[1]);
    __builtin_amdgcn_s_setprio(0);
  };

  loadAr(0,0); loadAr(1,1);
  loadWO_(0,0); loadWO_(1,1); loadWO_(2,2); loadWO_(3,3);
  loadWO_(4,4); loadWO_(5,5); loadWO_(6,6); loadWO_(7,7);
  #pragma unroll
  for(int kc=0; kc<8; kc+=2){
    stepA(0, kc);
    loadW1_(0, kc, kc);                   // refill set kc with B1-nch0 weights
    if(kc+2<8) loadAr(kc+2, 0);
    stepA(1, kc+1);
    loadW1_(0, kc+1, kc+1);
    if(kc+3<8) loadAr(kc+3, 1);
  }

  // epilogue A: + residual (prev-layer x, global), LN -> val_s regs + xA LDS
  // (B1-nch0 weight loads land under this VALU-heavy section)
  float tmp[2][4];
  #pragma unroll
  for(int cg=0;cg<2;cg++)
    #pragma unroll
    for(int r=0;r<4;r++){
      int row = row0 + Q*4 + r;
      int c = (w*2+cg)*16 + L15;
      tmp[cg][r] = accA[cg][r] + xf[(size_t)row*DD + c];
    }
  float s[4], sq[4];
  #pragma unroll
  for(int r=0;r<4;r++){
    s[r]  = tmp[0][r]+tmp[1][r];
    sq[r] = tmp[0][r]*tmp[0][r]+tmp[1][r]*tmp[1][r];
  }
  #pragma unroll
  for(int off=1; off<16; off<<=1)
    #pragma unroll
    for(int r=0;r<4;r++){
      s[r]  += __shfl_xor(s[r], off);
      sq[r] += __shfl_xor(sq[r], off);
    }
  if(L15==0){
    #pragma unroll
    for(int r=0;r<4;r++){
      int rl = Q*4 + r;
      lred[(w*16 + rl)*2]   = s[r];
      lred[(w*16 + rl)*2+1] = sq[r];
    }
  }
  __syncthreads();
  float val_s[2][4];
  {
    float g = gamma[gi0], bb = beta[gi0];
    float scv[4], mnv[4];
    #pragma unroll
    for(int r=0;r<4;r++){
      int rl = Q*4 + r;
      float S = 0.f, SQ = 0.f;
      #pragma unroll
      for(int wv=0; wv<8; wv++){
        S  += lred[(wv*16+rl)*2];
        SQ += lred[(wv*16+rl)*2+1];
      }
      float mean = S*(1.f/DD);
      float var  = SQ*(1.f/DD) - mean*mean;
      scv[r] = rsqrtf(var+LN_EPS)*g;
      mnv[r] = mean;
    }
    #pragma unroll
    for(int cg=0;cg<2;cg++){
      int c = (w*2+cg)*16 + L15;
      int base = (c>>5)*512 + (((c&31)>>3))*128 + (c&7);
      #pragma unroll
      for(int r=0;r<4;r++){
        float v = (tmp[cg][r]-mnv[r])*scv[r] + bb;
        val_s[cg][r] = v;
        us hb = f2bf_rne(v);
        xAH[base + (Q*4+r)*8] = hb;
        xAL[base + (Q*4+r)*8] = f2bf_rne(v - us2f(hb));
      }
    }
  }
  __syncthreads();                        // xA visible to all waves

  // ---------------- phase B1: h = relu(val@W1 + b1), continuous refill ----------------
  #pragma unroll
  for(int nch=0; nch<2; nch++){
    f32x4 ah[2];
    ah[0] = ah[1] = (f32x4){0.f,0.f,0.f,0.f};
    #pragma unroll
    for(int kc=0; kc<8; kc++){
      bf16x8 aAh = *(const bf16x8*)&xAH[kc*512 + lane*8];
      bf16x8 aAl = *(const bf16x8*)&xAL[kc*512 + lane*8];
      __builtin_amdgcn_s_setprio(1);
      ah[0] = MF(aAl, Wh[kc][0], ah[0]);
      ah[0] = MF(aAh, Wl[kc][0], ah[0]);
      ah[0] = MF(aAh, Wh[kc][0], ah[0]);
      ah[1] = MF(aAl, Wh[kc][1], ah[1]);
      ah[1] = MF(aAh, Wl[kc][1], ah[1]);
      ah[1] = MF(aAh, Wh[kc][1], ah[1]);
      __builtin_amdgcn_s_setprio(0);
      if(nch==0) loadW1_(1, kc, kc);      // refill with nch1 weights
      else       loadW2_(kc, kc);         // refill with B2 steps 0..7
    }
    #pragma unroll
    for(int cg=0;cg<2;cg++){
      int col = nch*256 + (w*2+cg)*16 + L15;
      float bv = b1[col];
      int base = (col>>5)*512 + (((col&31)>>3))*128 + (col&7);
      #pragma unroll
      for(int r=0;r<4;r++){
        int row = Q*4 + r;
        float v = ah[cg][r] + bv;
        v = v>0.f ? v : 0.f;
        us hb = f2bf_rne(v);
        hAH[base + row*8] = hb;
        hAL[base + row*8] = f2bf_rne(v - us2f(hb));
      }
    }
  }
  __syncthreads();                        // hA visible to all waves

  // ---------------- phase B2: y = h@W2 (16 steps, depth-8) ----------------
  f32x4 ay[2];
  ay[0] = ay[1] = (f32x4){0.f,0.f,0.f,0.f};
  #pragma unroll
  for(int kc2=0; kc2<16; kc2++){
    const int sub = kc2 & 7;
    bf16x8 aAh = *(const bf16x8*)&hAH[kc2*512 + lane*8];
    bf16x8 aAl = *(const bf16x8*)&hAL[kc2*512 + lane*8];
    __builtin_amdgcn_s_setprio(1);
    ay[0] = MF(aAl, Wh[sub][0], ay[0]);
    ay[0] = MF(aAh, Wl[sub][0], ay[0]);
    ay[0] = MF(aAh, Wh[sub][0], ay[0]);
    ay[1] = MF(aAl, Wh[sub][1], ay[1]);
    ay[1] = MF(aAh, Wl[sub][1], ay[1]);
    ay[1] = MF(aAh, Wh[sub][1], ay[1]);
    __builtin_amdgcn_s_setprio(0);
    if(kc2+8 < 16) loadW2_(kc2+8, sub);   // refill for steps 8..15
  }

  // ---------------- epilogue B: +b2 +val(res regs), LN, global writes ----------------
  float tmp2[2][4];
  #pragma unroll
  for(int cg=0;cg<2;cg++)
    #pragma unroll
    for(int r=0;r<4;r++){
      int c = (w*2+cg)*16 + L15;
      tmp2[cg][r] = ay[cg][r] + val_s[cg][r] + b2[c];
    }
  float s2[4], sq2[4];
  #pragma unroll
  for(int r=0;r<4;r++){
    s2[r]  = tmp2[0][r]+tmp2[1][r];
    sq2[r] = tmp2[0][r]*tmp2[0][r]+tmp2[1][r]*tmp2[1][r];
  }
  #pragma unroll
  for(int off=1; off<16; off<<=1)
    #pragma unroll
    for(int r=0;r<4;r++){
      s2[r]  += __shfl_xor(s2[r], off);
      sq2[r] += __shfl_xor(sq2[r], off);
    }
  if(L15==0){
    #pragma unroll
    for(int r=0;r<4;r++){
      int rl = Q*4 + r;
      lred[(w*16 + rl)*2]   = s2[r];
      lred[(w*16 + rl)*2+1] = sq2[r];
    }
  }
  __syncthreads();
  float g2 = gamma[gi0+1], bb2 = beta[gi0+1];
  float scv2[4], mnv2[4];
  #pragma unroll
  for(int r=0;r<4;r++){
    int rl = Q*4 + r;
    float S = 0.f, SQ = 0.f;
    #pragma unroll
    for(int wv=0; wv<8; wv++){
      S  += lred[(wv*16+rl)*2];
      SQ += lred[(wv*16+rl)*2+1];
    }
    float mean = S*(1.f/DD);
    float var  = SQ*(1.f/DD) - mean*mean;
    scv2[r] = rsqrtf(var+LN_EPS)*g2;
    mnv2[r] = mean;
  }
  int flag = write_out ? *flagp : 0;
  #pragma unroll
  for(int cg=0;cg<2;cg++)
    #pragma unroll
    for(int r=0;r<4;r++){
      int row = row0 + Q*4 + r;
      int c = (w*2+cg)*16 + L15;
      float val = (tmp2[cg][r]-mnv2[r])*scv2[r] + bb2;
      xf[(size_t)row*DD + c] = val;
      us hb = f2bf_rne(val);
      size_t xi = xhl_idx(row, c);
      xh[xi] = hb;
      xl[xi] = f2bf_rne(val - us2f(hb));
      if(write_out){
        if(flag) ((float*)out)[(size_t)row*DD + c] = val;
        else     ((bf16*)out)[(size_t)row*DD + c] = __float2bfloat16(val);
      }
    }
}

// MFMA flash attention: v9 double-buffer schedule; full 1024-float mask row
// staged ONCE at prologue via one gl_lds16.  T5 s_setprio(1) around MFMA
// clusters (R11: part of the 247.5->239.9 win).
__launch_bounds__(256)
__global__ void attn_kernel(const us* __restrict__ QH, const us* __restrict__ QL,
                            const us* __restrict__ KH, const us* __restrict__ KL,
                            const us* __restrict__ VT,
                            const float* __restrict__ mask,
                            float* __restrict__ Opart, float* __restrict__ ML)
{
  __shared__ __align__(16) us Khs[4096], Kls[4096], Vts[4096];  // 2 bufs x 2048
  __shared__ __align__(16) float Msl[1024];                      // full ks-half mask
  const int t = threadIdx.x;
  const int bh = blockIdx.x >> 6;
  const int qt = (blockIdx.x & 63) >> 1;
  const int ks = blockIdx.x & 1;
  const int b_ = bh >> 3;
  const int wv = t >> 6;
  const int lane = t & 63;
  const int Q = lane >> 4, L15 = lane & 15;
  const int q0 = qt*64 + wv*16;

  size_t qidx = ((size_t)(bh*128 + qt*4 + wv)*64 + lane)*8;
  const bf16x8 qh_v = *(const bf16x8*)&QH[qidx];
  const bf16x8 ql_v = *(const bf16x8*)&QL[qidx];

  const us* KHbh = KH + (size_t)bh*65536;
  const us* KLbh = KL + (size_t)bh*65536;
  const us* VTbh = VT + (size_t)bh*65536;
  const int base = ks*1024;

  f32x4 Oa0a = {0.f,0.f,0.f,0.f}, Oa0b = {0.f,0.f,0.f,0.f};
  f32x4 Oa1a = {0.f,0.f,0.f,0.f}, Oa1b = {0.f,0.f,0.f,0.f};
  float lacc = 0.f;

  // prologue: mask row (1 async op) + stage 0 into buffer 0
  {
    const us* mrow = (const us*)(mask + (size_t)b_*SS + base);
    gl_lds16(mrow + (size_t)t*8, ((us*)Msl) + t*8);
    size_t kbase = (size_t)(base>>4)*512;
    size_t vbase = (size_t)(base>>5)*1024;
    gl_lds16(&KHbh[kbase + (size_t)t*8], &Khs[t*8]);
    gl_lds16(&KLbh[kbase + (size_t)t*8], &Kls[t*8]);
    gl_lds16(&VTbh[vbase + (size_t)t*8], &Vts[t*8]);
  }

  for(int s=0; s<16; s++){
    __syncthreads();                         // drains loads(s); orders buffer reuse
    if(s < 15){
      int t0n = base + (s+1)*64;
      int bn = (s+1)&1;
      size_t kbase = (size_t)(t0n>>4)*512;
      size_t vbase = (size_t)(t0n>>5)*1024;
      gl_lds16(&KHbh[kbase + (size_t)t*8], &Khs[bn*2048 + t*8]);
      gl_lds16(&KLbh[kbase + (size_t)t*8], &Kls[bn*2048 + t*8]);
      gl_lds16(&VTbh[vbase + (size_t)t*8], &Vts[bn*2048 + t*8]);
    }
    const int bo = (s&1)*2048;
    const int mo = s*64;

    // QK^T -> S^T (3 MFMAs per 16-key tile, 4 tiles)
    f32x4 St[4];
    const f32x4 zz = {0.f,0.f,0.f,0.f};
    __builtin_amdgcn_s_setprio(1);
    #pragma unroll
    for(int kt=0;kt<4;kt++){
      bf16x8 aKh = *(const bf16x8*)&Khs[bo + kt*512 + lane*8];
      bf16x8 aKl = *(const bf16x8*)&Kls[bo + kt*512 + lane*8];
      f32x4 a = MF(aKl, qh_v, zz);
      a = MF(aKh, ql_v, a);
      a = MF(aKh, qh_v, a);
      St[kt] = a;
    }
    __builtin_amdgcn_s_setprio(0);

    // fixed-shift softmax in log2 space
    float lsum = 0.f;
    #pragma unroll
    for(int kt=0;kt<4;kt++){
      float4 mv = *(const float4*)&Msl[mo + kt*16 + Q*4];
      float mvr[4] = {mv.x, mv.y, mv.z, mv.w};
      #pragma unroll
      for(int r=0;r<4;r++){
        float p = EXP2F(fmaf(mvr[r], St[kt][r], -SOFT_SHIFT_L2E));
        St[kt][r] = p;
        lsum += p;
      }
    }
    lacc += lsum;

    // pack P -> bf16 pairs
    int pk[4][2];
    #pragma unroll
    for(int kt=0;kt<4;kt++){
      pk[kt][0] = pack_bf16(St[kt][0], St[kt][1]);
      pk[kt][1] = pack_bf16(St[kt][2], St[kt][3]);
    }

    // PV: O^T += V^T · P^T (2 chunks of 32 keys; c0 -> a regs, c1 -> b regs)
    #pragma unroll
    for(int c=0;c<2;c++){
      union { int i[4]; bf16x8 v; } bu;
      #pragma unroll
      for(int d=0;d<4;d++){
        int srcl = (((Q&1)*2 + (d>>1))<<4) | L15;
        int vlo = __shfl(pk[2*c  ][d&1], srcl, 64);
        int vhi = __shfl(pk[2*c+1][d&1], srcl, 64);
        bu.i[d] = (Q & 2) ? vhi : vlo;
      }
      bf16x8 aV0 = *(const bf16x8*)&Vts[bo + (c*2+0)*512 + lane*8];
      bf16x8 aV1 = *(const bf16x8*)&Vts[bo + (c*2+1)*512 + lane*8];
      __builtin_amdgcn_s_setprio(1);
      if(c == 0){
        Oa0a = MF(aV0, bu.v, Oa0a);
        Oa1a = MF(aV1, bu.v, Oa1a);
      } else {
        Oa0b = MF(aV0, bu.v, Oa0b);
        Oa1b = MF(aV1, bu.v, Oa1b);
      }
      __builtin_amdgcn_s_setprio(0);
    }
  }

  f32x4 Oa0 = Oa0a + Oa0b;
  f32x4 Oa1 = Oa1a + Oa1b;
  lacc += __shfl_xor(lacc, 16);
  lacc += __shfl_xor(lacc, 32);

  float* opp = &Opart[((size_t)(ks*16+bh)*SS + q0 + L15)*32];
  #pragma unroll
  for(int r=0;r<4;r++){
    opp[Q*4+r]    = Oa0[r];
    opp[16+Q*4+r] = Oa1[r];
  }
  if(Q==0){
    ML[(size_t)(ks*16+bh)*SS + q0 + L15] = lacc;
  }
}

extern "C" void kernel_launch(void* const* d_in, const int* in_sizes, int n_in,
                              void* d_out, int out_size, void* d_ws, size_t ws_size,
                              hipStream_t stream)
{
  float* ws = (float*)d_ws;
  int* flagp = (int*)d_ws;

  float* xf  = ws + O_XF;
  us* QHb = (us*)(ws + O_QB);
  us* QLb = QHb + 1048576;
  us* KH = (us*)(ws + O_KH);
  us* KL = (us*)(ws + O_KL);
  us* VT = (us*)(ws + O_VT);
  us* XH = (us*)(ws + O_XH);
  us* XL = (us*)(ws + O_XL);
  float* Opart = ws + O_OP;
  float* ML  = ws + O_ML;
  float* b1f = ws + O_B1;
  float* b2f_ = ws + O_B2;
  float* gmf = ws + O_GM;
  float* btf = ws + O_BT;
  us* prep = (us*)(ws + O_PREP);

  conv_prep<<<PREP_BLOCKS+CONV_BLOCKS,256,0,stream>>>(
      d_in[0], d_in[1], d_in[2], d_in[3], d_in[4], d_in[5],
      d_in[6], d_in[7], d_in[8], d_in[9], d_in[10], d_in[11],
      ws, flagp);

  for(int i=0;i<NL;i++){
    const float* b1i = b1f + (size_t)i*DFF;
    const float* b2i = b2f_ + (size_t)i*DD;

    dim3 g0(64, 12);
    gemm_mfma<0><<<g0,256,0,stream>>>(XH, XL,
                                      prep+PQH+(size_t)i*196608, prep+PQL+(size_t)i*196608,
                                      nullptr, nullptr,
                                      QHb, QLb, KH, KL, VT, 768, 256);
    attn_kernel<<<1024,256,0,stream>>>(QHb, QLb, KH, KL, VT, ws + O_MASK, Opart, ML);
    oln_ffn<<<256,512,0,stream>>>(Opart, ML,
                                  prep+POH+(size_t)i*65536, prep+POL+(size_t)i*65536,
                                  prep+P1H+(size_t)i*131072, prep+P1L+(size_t)i*131072,
                                  prep+P2H+(size_t)i*131072, prep+P2L+(size_t)i*131072,
                                  b1i, b2i, xf, XH, XL,
                                  gmf, btf, 2*i, d_out, (i==NL-1)?1:0, flagp);
  }
}